// Round 2
// baseline (81.996 us; speedup 1.0000x reference)
//
#include <hip/hip_runtime.h>
#include <hip/hip_bf16.h>

#define BATCH 4
#define NPTS 8192
#define TPB 256
#define RSPLIT 4                    // row-split partial-min slices (no atomics)
#define TOTAL (2 * BATCH * NPTS)    // 65536 output slots
#define GRID (8 * 32 * RSPLIT)      // sides x colgroups x rowsplit = 1024 blocks

// Packed-fragment geometry, in 16-byte units.
// Per point: 2 units (lo = k0..7, hi = k8..15). Unit order is the MFMA
// lane order: unit (p>>5)*64 + (p&31) holds lo, +32 holds hi, so a wave's
// global_load_dwordx4 at (tile*64 + lane)*16B is a coalesced 1KB A-operand.
#define UNITS_PER_BATCH (NPTS * 2)                   // 16384
#define UNITS_PER_TENSOR (BATCH * UNITS_PER_BATCH)   // 65536  (1 MB)
#define ROLE_B_OFF (2 * UNITS_PER_TENSOR)            // roleA region then roleB

typedef short bf16x8 __attribute__((ext_vector_type(8)));
typedef float f32x16 __attribute__((ext_vector_type(16)));

__device__ __forceinline__ unsigned short b16(float f) {   // fp32 -> bf16 RNE (HW cvt)
  __hip_bfloat16 h = __float2bfloat16(f);
  return __builtin_bit_cast(unsigned short, h);
}
__device__ __forceinline__ float b2f(unsigned short h) {
  return __uint_as_float(((unsigned)h) << 16);
}

// K=16 packed rows (R8/R10/R11-verified exact, absmax 0.0):
//  roleA(x): [(-2x)h(3), (-2x)l(3), (-2x)h(3), x2h, x2l, 1,   1,  0,0,0]
//  roleB(y): [yh(3),     yh(3),     yl(3),     1,   1, y2h, y2l, 0,0,0]
// roleA.roleB = squared distance minus (-2x)l.yl (~1e-5 << 9.3e-4 threshold).
__device__ __forceinline__ void pack_halves(uint4* lo, uint4* hi, float cx,
                                            float cy, float cz, bool roleA) {
  float n2 = cx * cx + cy * cy + cz * cz;
  float vx = roleA ? -2.f * cx : cx;
  float vy = roleA ? -2.f * cy : cy;
  float vz = roleA ? -2.f * cz : cz;
  unsigned hx = b16(vx), hy = b16(vy), hz = b16(vz);
  unsigned lx = b16(vx - b2f(hx)), ly = b16(vy - b2f(hy)), lz = b16(vz - b2f(hz));
  unsigned nh = b16(n2), nl = b16(n2 - b2f(nh));
  const unsigned ONE = 0x3F80u;
  if (roleA) {
    *lo = make_uint4(hx | (hy << 16), hz | (lx << 16), ly | (lz << 16), hx | (hy << 16));
    *hi = make_uint4(hz | (nh << 16), nl | (ONE << 16), ONE, 0u);
  } else {
    *lo = make_uint4(hx | (hy << 16), hz | (hx << 16), hy | (hz << 16), lx | (ly << 16));
    *hi = make_uint4(lz | (ONE << 16), ONE | (nh << 16), nl, 0u);
  }
}

// R13 pre-pack: one thread per point, writes BOTH role fragments to global
// in MFMA lane order. 65536 threads total; also zeroes the output slot.
__global__ __launch_bounds__(TPB) void chamfer_prepack(
    const float* __restrict__ pred, const float* __restrict__ gt,
    uint4* __restrict__ pk, float* __restrict__ out) {
  int g = blockIdx.x * TPB + threadIdx.x;
  if (g == 0) out[0] = 0.f;            // zero accumulator for reduce pass
  int tensor = g >> 15;                // 0 = pred, 1 = gt
  int b = (g >> 13) & 3, p = g & 8191;
  const float* src = (tensor ? gt : pred) + ((size_t)(b * NPTS + p)) * 3;
  float cx = src[0], cy = src[1], cz = src[2];
  size_t ubase = (size_t)tensor * UNITS_PER_TENSOR +
                 (size_t)b * UNITS_PER_BATCH + (p >> 5) * 64 + (p & 31);
  uint4 lo, hi;
  pack_halves(&lo, &hi, cx, cy, cz, true);    // roleA (row side)
  pk[ubase] = lo;
  pk[ubase + 32] = hi;
  pack_halves(&lo, &hi, cx, cy, cz, false);   // roleB (col side)
  pk[ROLE_B_OFF + ubase] = lo;
  pk[ROLE_B_OFF + ubase + 32] = hi;
}

// R13 NN pass: ZERO LDS, ZERO barriers. Fragments stream from the packed
// global buffers (L2-hot: 256 KB per side/batch) with coalesced 16B loads,
// 2-deep register prefetch; compiler pipelines vmcnt naturally. Per wave:
// 2 resident col-frags, 64 row-frag loads, 128 MFMA-pairs... (64 iters x
// [1 load + 2 MFMA + 16 v_min3]). Row-axis min stays in-lane (C/D layout
// col=lane&31, row=(reg&3)+8*(reg>>2)+4*(lane>>5); R10/R11-verified),
// shfl_xor(32) merge, coalesced partial stores. Same math as R12 bit-for-bit.
__global__ __launch_bounds__(TPB, 4) void chamfer_nn(
    const uint4* __restrict__ pk, float* __restrict__ partial) {
  int blk = blockIdx.x;
  int rq   = blk & (RSPLIT - 1);      // row quarter (64 rowtiles)
  int cg   = (blk >> 2) & 31;        // colgroup (256 cols = 8 tiles)
  int side = blk >> 7;               // dir*4 + b
  int dir = side >> 2, b = side & 3;

  // dir0: cols=pred(roleB), rows=gt(roleA). dir1: cols=gt, rows=pred.
  const uint4* colPk = pk + ROLE_B_OFF +
      (size_t)(dir ? 1 : 0) * UNITS_PER_TENSOR + (size_t)b * UNITS_PER_BATCH;
  const uint4* rowPk = pk +
      (size_t)(dir ? 0 : 1) * UNITS_PER_TENSOR + (size_t)b * UNITS_PER_BATCH;

  int t = threadIdx.x, w = t >> 6, lane = t & 63;

  // Resident col-operands: wave w owns col-tiles cg*8 + {2w, 2w+1}.
  bf16x8 af0 = *(const bf16x8*)&colPk[(cg * 8 + 2 * w) * 64 + lane];
  bf16x8 af1 = *(const bf16x8*)&colPk[(cg * 8 + 2 * w + 1) * 64 + lane];

  const uint4* rbase = rowPk + (size_t)rq * (64 * 64) + lane;

  const f32x16 Z = {0.f,0.f,0.f,0.f,0.f,0.f,0.f,0.f,0.f,0.f,0.f,0.f,0.f,0.f,0.f,0.f};
  float m0 = 3.4e38f, m1 = 3.4e38f;

#define FOLD(bfv) do {                                                       \
    f32x16 d0 = __builtin_amdgcn_mfma_f32_32x32x16_bf16(bfv, af0, Z, 0, 0, 0); \
    f32x16 d1 = __builtin_amdgcn_mfma_f32_32x32x16_bf16(bfv, af1, Z, 0, 0, 0); \
    _Pragma("unroll")                                                        \
    for (int r = 0; r < 16; r += 2) {                                        \
      m0 = fminf(fminf(m0, d0[r]), d0[r + 1]);   /* v_min3_f32 */            \
      m1 = fminf(fminf(m1, d1[r]), d1[r + 1]);                               \
    }                                                                        \
  } while (0)

  bf16x8 c0 = *(const bf16x8*)&rbase[0 * 64];
  bf16x8 c1 = *(const bf16x8*)&rbase[1 * 64];
  #pragma unroll 1
  for (int rt = 0; rt < 62; rt += 2) {
    bf16x8 n0 = *(const bf16x8*)&rbase[(rt + 2) * 64];
    bf16x8 n1 = *(const bf16x8*)&rbase[(rt + 3) * 64];
    FOLD(c0);
    FOLD(c1);
    c0 = n0;
    c1 = n1;
  }
  FOLD(c0);
  FOLD(c1);
#undef FOLD

  m0 = fminf(m0, __shfl_xor(m0, 32, 64));   // merge complementary row halves
  m1 = fminf(m1, __shfl_xor(m1, 32, 64));
  if (lane < 32) {
    float* dst = partial + (size_t)rq * TOTAL + (size_t)side * NPTS + cg * 256;
    dst[w * 64 + lane]      = fmaxf(m0, 0.f);
    dst[w * 64 + 32 + lane] = fmaxf(m1, 0.f);
  }
}

// Reduce: min over RSPLIT partials per slot, block-sum, one atomicAdd/block.
// out[0] was zeroed by chamfer_prepack (stream-ordered before this kernel).
__global__ __launch_bounds__(TPB) void chamfer_reduce(
    const float* __restrict__ partial, float* __restrict__ out) {
  int t = threadIdx.x;
  int s = blockIdx.x * TPB + t;       // slot 0..65535
  float v = partial[s];
  #pragma unroll
  for (int r = 1; r < RSPLIT; ++r)
    v = fminf(v, partial[(size_t)r * TOTAL + s]);
  #pragma unroll
  for (int off = 32; off > 0; off >>= 1) v += __shfl_down(v, off, 64);
  __shared__ float wsum[4];
  int wave = t >> 6, lane = t & 63;
  if (lane == 0) wsum[wave] = v;
  __syncthreads();
  if (t == 0) {
    float tot = (wsum[0] + wsum[1]) + (wsum[2] + wsum[3]);
    atomicAdd(out, tot * (1.f / (float)(BATCH * NPTS)));
  }
}

extern "C" void kernel_launch(void* const* d_in, const int* in_sizes, int n_in,
                              void* d_out, int out_size, void* d_ws, size_t ws_size,
                              hipStream_t stream) {
  const float* pred = (const float*)d_in[0];
  const float* gt   = (const float*)d_in[1];
  float* out        = (float*)d_out;
  float* partial    = (float*)d_ws;   // RSPLIT x 65536 floats = 1 MB
  uint4* pk = (uint4*)((char*)d_ws + (size_t)RSPLIT * TOTAL * sizeof(float)); // 4 MB

  chamfer_prepack<<<dim3(TOTAL / TPB), dim3(TPB), 0, stream>>>(pred, gt, pk, out);
  chamfer_nn<<<dim3(GRID), dim3(TPB), 0, stream>>>(pk, partial);
  chamfer_reduce<<<dim3(TOTAL / TPB), dim3(TPB), 0, stream>>>(partial, out);
}

// Round 3
// 80.476 us; speedup vs baseline: 1.0189x; 1.0189x over previous
//
#include <hip/hip_runtime.h>
#include <hip/hip_bf16.h>

#define BATCH 4
#define NPTS 8192
#define TPB 256
#define RSPLIT 8                    // row-split partial-min slices (no atomics)
#define CGROUPS 16                  // colgroups per side (512 cols each)
#define TOTAL (2 * BATCH * NPTS)    // 65536 output slots
#define GRID (8 * CGROUPS * RSPLIT) // 1024 blocks, 4/CU

// Packed-fragment geometry, in 16-byte units.
// Per point: 2 units (lo = k0..7, hi = k8..15). Unit order is the MFMA
// lane order: unit (p>>5)*64 + (p&31) holds lo, +32 holds hi, so a wave's
// global_load_dwordx4 at (tile*64 + lane)*16B is a coalesced 1KB operand.
#define UNITS_PER_BATCH (NPTS * 2)                   // 16384
#define UNITS_PER_TENSOR (BATCH * UNITS_PER_BATCH)   // 65536  (1 MB)
#define ROLE_B_OFF (2 * UNITS_PER_TENSOR)            // roleA region then roleB

typedef short bf16x8 __attribute__((ext_vector_type(8)));
typedef float f32x16 __attribute__((ext_vector_type(16)));

__device__ __forceinline__ unsigned short b16(float f) {   // fp32 -> bf16 RNE (HW cvt)
  __hip_bfloat16 h = __float2bfloat16(f);
  return __builtin_bit_cast(unsigned short, h);
}
__device__ __forceinline__ float b2f(unsigned short h) {
  return __uint_as_float(((unsigned)h) << 16);
}

// K=16 packed rows (R8/R10/R11-verified exact, absmax 0.0):
//  roleA(x): [(-2x)h(3), (-2x)l(3), (-2x)h(3), x2h, x2l, 1,   1,  0,0,0]
//  roleB(y): [yh(3),     yh(3),     yl(3),     1,   1, y2h, y2l, 0,0,0]
// roleA.roleB = squared distance minus (-2x)l.yl (~1e-5 << 9.3e-4 threshold).
__device__ __forceinline__ void pack_halves(uint4* lo, uint4* hi, float cx,
                                            float cy, float cz, bool roleA) {
  float n2 = cx * cx + cy * cy + cz * cz;
  float vx = roleA ? -2.f * cx : cx;
  float vy = roleA ? -2.f * cy : cy;
  float vz = roleA ? -2.f * cz : cz;
  unsigned hx = b16(vx), hy = b16(vy), hz = b16(vz);
  unsigned lx = b16(vx - b2f(hx)), ly = b16(vy - b2f(hy)), lz = b16(vz - b2f(hz));
  unsigned nh = b16(n2), nl = b16(n2 - b2f(nh));
  const unsigned ONE = 0x3F80u;
  if (roleA) {
    *lo = make_uint4(hx | (hy << 16), hz | (lx << 16), ly | (lz << 16), hx | (hy << 16));
    *hi = make_uint4(hz | (nh << 16), nl | (ONE << 16), ONE, 0u);
  } else {
    *lo = make_uint4(hx | (hy << 16), hz | (hx << 16), hy | (hz << 16), lx | (ly << 16));
    *hi = make_uint4(lz | (ONE << 16), ONE | (nh << 16), nl, 0u);
  }
}

// Pre-pack: one thread per point, writes BOTH role fragments to global
// in MFMA lane order. 65536 threads total; also zeroes the output slot.
__global__ __launch_bounds__(TPB) void chamfer_prepack(
    const float* __restrict__ pred, const float* __restrict__ gt,
    uint4* __restrict__ pk, float* __restrict__ out) {
  int g = blockIdx.x * TPB + threadIdx.x;
  if (g == 0) out[0] = 0.f;            // zero accumulator for reduce pass
  int tensor = g >> 15;                // 0 = pred, 1 = gt
  int b = (g >> 13) & 3, p = g & 8191;
  const float* src = (tensor ? gt : pred) + ((size_t)(b * NPTS + p)) * 3;
  float cx = src[0], cy = src[1], cz = src[2];
  size_t ubase = (size_t)tensor * UNITS_PER_TENSOR +
                 (size_t)b * UNITS_PER_BATCH + (p >> 5) * 64 + (p & 31);
  uint4 lo, hi;
  pack_halves(&lo, &hi, cx, cy, cz, true);    // roleA (row side)
  pk[ubase] = lo;
  pk[ubase + 32] = hi;
  pack_halves(&lo, &hi, cx, cy, cz, false);   // roleB (col side)
  pk[ROLE_B_OFF + ubase] = lo;
  pk[ROLE_B_OFF + ubase + 32] = hi;
}

// R14 NN pass: zero LDS/barriers, but now 4 col-tiles resident PER WAVE
// (512 cols/block) and RSPLIT=8 (1024 rows/block). Each row-tile load
// feeds 4 MFMA + 32 v_min3 (~64 VALU cyc); x4 waves/SIMD + 2-tile-ahead
// prefetch => ~400+ cyc of slack per load, covering L2/L3 latency that
// R12/R13 (32 cyc/load) both stalled on. Row-fragment L2 traffic halves.
// Min fold is a depth-3 min3 tree (bit-identical; min is reorder-exact).
// Row-axis min stays in-lane (C/D layout col=lane&31,
// row=(reg&3)+8*(reg>>2)+4*(lane>>5); R10/R11-verified), shfl_xor(32)
// merge, coalesced 128B partial stores.
__global__ __launch_bounds__(TPB, 4) void chamfer_nn(
    const uint4* __restrict__ pk, float* __restrict__ partial) {
  int blk = blockIdx.x;
  int rq   = blk & (RSPLIT - 1);       // row slice (1024 rows = 32 tiles)
  int cg   = (blk >> 3) & (CGROUPS - 1); // colgroup (512 cols = 16 tiles)
  int side = blk >> 7;                 // dir*4 + b
  int dir = side >> 2, b = side & 3;

  // dir0: cols=pred(roleB), rows=gt(roleA). dir1: cols=gt, rows=pred.
  const uint4* colPk = pk + ROLE_B_OFF +
      (size_t)(dir ? 1 : 0) * UNITS_PER_TENSOR + (size_t)b * UNITS_PER_BATCH;
  const uint4* rowPk = pk +
      (size_t)(dir ? 0 : 1) * UNITS_PER_TENSOR + (size_t)b * UNITS_PER_BATCH;

  int t = threadIdx.x, w = t >> 6, lane = t & 63;

  // Resident col-operands: wave w owns col-tiles cg*16 + w*4 + {0..3}.
  bf16x8 af[4];
  #pragma unroll
  for (int j = 0; j < 4; ++j)
    af[j] = *(const bf16x8*)&colPk[(cg * 16 + w * 4 + j) * 64 + lane];

  const uint4* rbase = rowPk + (size_t)rq * 2048 + lane;

  const f32x16 Z = {0.f,0.f,0.f,0.f,0.f,0.f,0.f,0.f,0.f,0.f,0.f,0.f,0.f,0.f,0.f,0.f};
  float m[4] = {3.4e38f, 3.4e38f, 3.4e38f, 3.4e38f};

  // One MFMA + depth-3 min3 tree per col-tile; d consumed before next MFMA
  // so only one f32x16 temp is live (VGPR <= ~100, no spill at 4 waves/EU).
#define FOLD4(bfv) do {                                                      \
    _Pragma("unroll")                                                        \
    for (int j = 0; j < 4; ++j) {                                            \
      f32x16 d = __builtin_amdgcn_mfma_f32_32x32x16_bf16(bfv, af[j], Z, 0, 0, 0); \
      float t0 = fminf(fminf(d[0], d[1]), d[2]);                             \
      float t1 = fminf(fminf(d[3], d[4]), d[5]);                             \
      float t2 = fminf(fminf(d[6], d[7]), d[8]);                             \
      float t3 = fminf(fminf(d[9], d[10]), d[11]);                           \
      float t4 = fminf(fminf(d[12], d[13]), d[14]);                          \
      float u0 = fminf(fminf(t0, t1), d[15]);                                \
      float u1 = fminf(fminf(t2, t3), t4);                                   \
      m[j] = fminf(fminf(m[j], u0), u1);                                     \
    }                                                                        \
  } while (0)

  bf16x8 c0 = *(const bf16x8*)&rbase[0 * 64];
  bf16x8 c1 = *(const bf16x8*)&rbase[1 * 64];
  #pragma unroll 1
  for (int rt = 0; rt < 30; rt += 2) {
    bf16x8 n0 = *(const bf16x8*)&rbase[(rt + 2) * 64];
    bf16x8 n1 = *(const bf16x8*)&rbase[(rt + 3) * 64];
    FOLD4(c0);
    FOLD4(c1);
    c0 = n0;
    c1 = n1;
  }
  FOLD4(c0);
  FOLD4(c1);
#undef FOLD4

  #pragma unroll
  for (int j = 0; j < 4; ++j)
    m[j] = fminf(m[j], __shfl_xor(m[j], 32, 64));  // merge row halves
  if (lane < 32) {
    float* dst = partial + (size_t)rq * TOTAL + (size_t)side * NPTS;
    #pragma unroll
    for (int j = 0; j < 4; ++j)
      dst[(cg * 16 + w * 4 + j) * 32 + lane] = fmaxf(m[j], 0.f);
  }
}

// Reduce: min over RSPLIT partials per slot, block-sum, one atomicAdd/block.
// out[0] was zeroed by chamfer_prepack (stream-ordered before this kernel).
__global__ __launch_bounds__(TPB) void chamfer_reduce(
    const float* __restrict__ partial, float* __restrict__ out) {
  int t = threadIdx.x;
  int s = blockIdx.x * TPB + t;       // slot 0..65535
  float v = partial[s];
  #pragma unroll
  for (int r = 1; r < RSPLIT; ++r)
    v = fminf(v, partial[(size_t)r * TOTAL + s]);
  #pragma unroll
  for (int off = 32; off > 0; off >>= 1) v += __shfl_down(v, off, 64);
  __shared__ float wsum[4];
  int wave = t >> 6, lane = t & 63;
  if (lane == 0) wsum[wave] = v;
  __syncthreads();
  if (t == 0) {
    float tot = (wsum[0] + wsum[1]) + (wsum[2] + wsum[3]);
    atomicAdd(out, tot * (1.f / (float)(BATCH * NPTS)));
  }
}

extern "C" void kernel_launch(void* const* d_in, const int* in_sizes, int n_in,
                              void* d_out, int out_size, void* d_ws, size_t ws_size,
                              hipStream_t stream) {
  const float* pred = (const float*)d_in[0];
  const float* gt   = (const float*)d_in[1];
  float* out        = (float*)d_out;
  float* partial    = (float*)d_ws;   // RSPLIT x 65536 floats = 2 MB
  uint4* pk = (uint4*)((char*)d_ws + (size_t)RSPLIT * TOTAL * sizeof(float)); // 4 MB

  chamfer_prepack<<<dim3(TOTAL / TPB), dim3(TPB), 0, stream>>>(pred, gt, pk, out);
  chamfer_nn<<<dim3(GRID), dim3(TPB), 0, stream>>>(pk, partial);
  chamfer_reduce<<<dim3(TOTAL / TPB), dim3(TPB), 0, stream>>>(partial, out);
}

// Round 4
// 74.458 us; speedup vs baseline: 1.1012x; 1.0808x over previous
//
#include <hip/hip_runtime.h>
#include <hip/hip_bf16.h>

#define BATCH 4
#define NPTS 8192
#define TPB 256
#define RSPLIT 8                    // row-split partial-min slices (no atomics)
#define CGROUPS 16                  // colgroups per side (512 cols each)
#define TOTAL (2 * BATCH * NPTS)    // 65536 output slots
#define GRID (8 * CGROUPS * RSPLIT) // 1024 blocks, 4/CU

typedef short bf16x8 __attribute__((ext_vector_type(8)));
typedef float f32x16 __attribute__((ext_vector_type(16)));

__device__ __forceinline__ unsigned short b16(float f) {   // fp32 -> bf16 RNE (HW cvt)
  __hip_bfloat16 h = __float2bfloat16(f);
  return __builtin_bit_cast(unsigned short, h);
}
__device__ __forceinline__ float b2f(unsigned short h) {
  return __uint_as_float(((unsigned)h) << 16);
}

// K=16 packed rows (R8/R10/R11-verified exact, absmax 0.0):
//  roleA(x): [(-2x)h(3), (-2x)l(3), (-2x)h(3), x2h, x2l, 1,   1,  0,0,0]
//  roleB(y): [yh(3),     yh(3),     yl(3),     1,   1, y2h, y2l, 0,0,0]
// roleA.roleB = squared distance minus (-2x)l.yl (~1e-5 << 9.3e-4 threshold).
__device__ __forceinline__ void pack_halves(uint4* lo, uint4* hi, float cx,
                                            float cy, float cz, bool roleA) {
  float n2 = cx * cx + cy * cy + cz * cz;
  float vx = roleA ? -2.f * cx : cx;
  float vy = roleA ? -2.f * cy : cy;
  float vz = roleA ? -2.f * cz : cz;
  unsigned hx = b16(vx), hy = b16(vy), hz = b16(vz);
  unsigned lx = b16(vx - b2f(hx)), ly = b16(vy - b2f(hy)), lz = b16(vz - b2f(hz));
  unsigned nh = b16(n2), nl = b16(n2 - b2f(nh));
  const unsigned ONE = 0x3F80u;
  if (roleA) {
    *lo = make_uint4(hx | (hy << 16), hz | (lx << 16), ly | (lz << 16), hx | (hy << 16));
    *hi = make_uint4(hz | (nh << 16), nl | (ONE << 16), ONE, 0u);
  } else {
    *lo = make_uint4(hx | (hy << 16), hz | (hx << 16), hy | (hz << 16), lx | (ly << 16));
    *hi = make_uint4(lz | (ONE << 16), ONE | (nh << 16), nl, 0u);
  }
}

// R15 NN pass — 2-launch total (harness overhead dominates; minimize
// launches + cold starts). No prepack kernel, no packed global buffer.
//  * Col operands packed IN-REGISTER per wave (lane l packs col point
//    32*tile+(l&31), keeps lo half if l<32 else hi — bit-identical to the
//    old prepack bytes). No sA, no barrier for cols.
//  * Row operands staged once to LDS (32 KB = all 1024 rows), 4 pts/thread,
//    ONE __syncthreads, then 32 tiles x [ds_read_b128 + 4 MFMA + min3 tree].
//    LDS layout lane-ordered (R12-verified): unit (p>>5)*64+(p&31), hi +32;
//    writer & reader both lane-stride-1 => 2-way alias max (free, m136).
//  * Row-axis min in-lane (C/D: col=lane&31, row=(reg&3)+8*(reg>>2)+4*g);
//    shfl_xor(32) merge; coalesced 128B partial stores per col tile.
__global__ __launch_bounds__(TPB, 4) void chamfer_nn(
    const float* __restrict__ pred, const float* __restrict__ gt,
    float* __restrict__ partial, float* __restrict__ out) {
  __shared__ __align__(16) unsigned short sB[1024 * 16];   // 32 KB row frags

  int blk = blockIdx.x;
  int rq   = blk & (RSPLIT - 1);         // row slice (1024 rows = 32 tiles)
  int cg   = (blk >> 3) & (CGROUPS - 1); // colgroup (512 cols = 16 tiles)
  int side = blk >> 7;                   // dir*4 + b
  int dir = side >> 2, b = side & 3;

  const float* As = (dir ? gt : pred) + (size_t)b * NPTS * 3;  // cols (outputs)
  const float* Bs = (dir ? pred : gt) + (size_t)b * NPTS * 3;  // rows (min'ed)

  int t = threadIdx.x, w = t >> 6, lane = t & 63;
  if (blk == 0 && t == 0) out[0] = 0.f;   // zero accumulator for reduce pass

  int rowbase = rq * 1024;

  // ---- Stage rows: 4 points/thread into lane-ordered LDS units. ----
  #pragma unroll
  for (int h = 0; h < 4; ++h) {
    int p = h * 256 + t;                 // local row 0..1023
    int gp = rowbase + p;
    uint4 lo, hi;
    pack_halves(&lo, &hi, Bs[gp * 3], Bs[gp * 3 + 1], Bs[gp * 3 + 2], true);
    unsigned short* u0 = sB + ((p >> 5) * 64 + (p & 31)) * 8;
    *(uint4*)u0 = lo;
    *(uint4*)(u0 + 32 * 8) = hi;
  }

  // ---- Col operands in-register: wave w owns col tiles cg*16+w*4+{0..3}.
  // Lane l packs point 32*tile+(l&31); keeps lo (l<32) or hi (l>=32).
  bf16x8 af[4];
  #pragma unroll
  for (int j = 0; j < 4; ++j) {
    int gp = (cg * 16 + w * 4 + j) * 32 + (lane & 31);
    uint4 lo, hi;
    pack_halves(&lo, &hi, As[gp * 3], As[gp * 3 + 1], As[gp * 3 + 2], false);
    uint4 sel = (lane < 32) ? lo : hi;
    af[j] = __builtin_bit_cast(bf16x8, sel);
  }

  __syncthreads();   // single barrier: rows staged

  const f32x16 Z = {0.f,0.f,0.f,0.f,0.f,0.f,0.f,0.f,0.f,0.f,0.f,0.f,0.f,0.f,0.f,0.f};
  float m[4] = {3.4e38f, 3.4e38f, 3.4e38f, 3.4e38f};

  // One MFMA + depth-3 min3 tree per col-tile; d consumed before next MFMA
  // so only one f32x16 temp is live (no spill at 4 waves/EU).
  #pragma unroll 2
  for (int rt = 0; rt < 32; ++rt) {
    bf16x8 bf = *(const bf16x8*)(sB + (rt * 64 + lane) * 8);
    #pragma unroll
    for (int j = 0; j < 4; ++j) {
      f32x16 d = __builtin_amdgcn_mfma_f32_32x32x16_bf16(bf, af[j], Z, 0, 0, 0);
      float t0 = fminf(fminf(d[0], d[1]), d[2]);
      float t1 = fminf(fminf(d[3], d[4]), d[5]);
      float t2 = fminf(fminf(d[6], d[7]), d[8]);
      float t3 = fminf(fminf(d[9], d[10]), d[11]);
      float t4 = fminf(fminf(d[12], d[13]), d[14]);
      float u0 = fminf(fminf(t0, t1), d[15]);
      float u1 = fminf(fminf(t2, t3), t4);
      m[j] = fminf(fminf(m[j], u0), u1);
    }
  }

  #pragma unroll
  for (int j = 0; j < 4; ++j)
    m[j] = fminf(m[j], __shfl_xor(m[j], 32, 64));  // merge row halves
  if (lane < 32) {
    float* dst = partial + (size_t)rq * TOTAL + (size_t)side * NPTS;
    #pragma unroll
    for (int j = 0; j < 4; ++j)
      dst[(cg * 16 + w * 4 + j) * 32 + lane] = fmaxf(m[j], 0.f);
  }
}

// Reduce: min over RSPLIT partials per slot, block-sum, one atomicAdd/block.
// out[0] was zeroed by chamfer_nn (stream-ordered before this kernel).
__global__ __launch_bounds__(TPB) void chamfer_reduce(
    const float* __restrict__ partial, float* __restrict__ out) {
  int t = threadIdx.x;
  int s = blockIdx.x * TPB + t;       // slot 0..65535
  float v = partial[s];
  #pragma unroll
  for (int r = 1; r < RSPLIT; ++r)
    v = fminf(v, partial[(size_t)r * TOTAL + s]);
  #pragma unroll
  for (int off = 32; off > 0; off >>= 1) v += __shfl_down(v, off, 64);
  __shared__ float wsum[4];
  int wave = t >> 6, lane = t & 63;
  if (lane == 0) wsum[wave] = v;
  __syncthreads();
  if (t == 0) {
    float tot = (wsum[0] + wsum[1]) + (wsum[2] + wsum[3]);
    atomicAdd(out, tot * (1.f / (float)(BATCH * NPTS)));
  }
}

extern "C" void kernel_launch(void* const* d_in, const int* in_sizes, int n_in,
                              void* d_out, int out_size, void* d_ws, size_t ws_size,
                              hipStream_t stream) {
  const float* pred = (const float*)d_in[0];
  const float* gt   = (const float*)d_in[1];
  float* out        = (float*)d_out;
  float* partial    = (float*)d_ws;   // RSPLIT x 65536 floats = 2 MB

  chamfer_nn<<<dim3(GRID), dim3(TPB), 0, stream>>>(pred, gt, partial, out);
  chamfer_reduce<<<dim3(TOTAL / TPB), dim3(TPB), 0, stream>>>(partial, out);
}